// Round 4
// baseline (442.078 us; speedup 1.0000x reference)
//
#include <hip/hip_runtime.h>
#include <hip/hip_bf16.h>
#include <math.h>

// FleetModel forward. Round 4: fused wave-sliced row engine
// (projLN + FFN + QKV in one kernel; weights stay SGPR-uniform per wave).
#define NB 128
#define NPOS 652
#define DD 32
#define NH 4
#define NVEH 64
#define ZSTRIDE 162          // 2 + 16*10
#define MROWS (NB*NPOS)      // 83456 = 1304 * 64
#define QSCALE 0.51011784f   // (1/sqrt(8)) * log2(e)

typedef _Float16 half4 __attribute__((ext_vector_type(4)));
typedef _Float16 half8 __attribute__((ext_vector_type(8)));
typedef float float4v __attribute__((ext_vector_type(4)));

__device__ __forceinline__ float wave_sum64(float v) {
  #pragma unroll
  for (int off = 32; off > 0; off >>= 1) v += __shfl_down(v, off);
  return v;
}

// ---------------------------------------------------------------- canvas ----
__global__ __launch_bounds__(256) void canvas_kernel(
    const float* __restrict__ states, const float* __restrict__ road_ctx,
    const float* __restrict__ pos_emb,
    const float* __restrict__ Wp, const float* __restrict__ bp,
    const float* __restrict__ Wv, const float* __restrict__ bv,
    const float* __restrict__ Wh, const float* __restrict__ bh,
    const float* __restrict__ Wc, const float* __restrict__ bc,
    const float* __restrict__ Wflow, const float* __restrict__ bflow,
    const float* __restrict__ Wsig, const float* __restrict__ bsig,
    float* __restrict__ x)
{
  int b = blockIdx.x;
  int tid = threadIdx.x;
  __shared__ float mvs[2];
  if (tid < 64) {
    float vx = states[(b*NVEH + tid)*4 + 2];
    float vy = states[(b*NVEH + tid)*4 + 3];
    vx = wave_sum64(vx); vy = wave_sum64(vy);
    if (tid == 0) { mvs[0] = vx * (1.f/64.f); mvs[1] = vy * (1.f/64.f); }
  }
  __syncthreads();
  float mv0 = mvs[0], mv1 = mvs[1];
  for (int i = tid; i < NPOS*DD; i += 256) {
    int p = i >> 5, d = i & 31;
    float val = pos_emb[i];
    if (p < 4) {
      val += mv0*Wflow[p*32 + d] + mv1*Wflow[128 + p*32 + d] + bflow[p*32 + d];
    } else {
      int q = p - 4, z = q / ZSTRIDE, r = q % ZSTRIDE;
      if (r == 0) {
        val += Wsig[d] + bsig[d];
      } else if (r >= 2) {
        int vr = r - 2, v = vr / 10, s = vr % 10;
        int n = z*16 + v;
        const float* st = states + (b*NVEH + n)*4;
        if (s == 0) {
          val += st[0]*Wp[d] + st[1]*Wp[32+d] + bp[d];
        } else if (s == 1) {
          val += st[2]*Wv[d] + st[3]*Wv[32+d] + bv[d];
        } else if (s == 2) {
          float sp = fmaxf(sqrtf(st[2]*st[2] + st[3]*st[3]), 0.1f);
          val += (st[2]/sp)*Wh[d] + (st[3]/sp)*Wh[32+d] + bh[d];
        } else if (s == 3) {
          const float* rc = road_ctx + (b*NVEH + n)*4;
          val += rc[0]*Wc[d] + rc[1]*Wc[32+d] + rc[2]*Wc[64+d] + rc[3]*Wc[96+d] + bc[d];
        }
      }
    }
    x[(size_t)b*NPOS*DD + i] = val;
  }
}

// -------------------------------------------------------------- rowengine ----
// Block = 256 threads = 4 waves, all covering the SAME 64 rows (lane = row).
// Each wave owns a column slice -> weight indices stay wave-uniform (SGPR).
//   DO_PROJ: t = o@Wo + bo + x_resid; LN1(g1,b1) -> y  (wave w: cols 8w..8w+8)
//   DO_FFN : h = relu(y@W1+b1) (wave w: cols 32w..); z = h@W2 partials,
//            cross-wave reduce; + b2 + y resid; LN2(g2,b2) -> xnew
//   DO_QKV : qkv = xnew@Wqkv + bqkv (wave w: cols 24w..24w+24) -> f16 q/k/v^T
// Cross-wave traffic via LDS (stride 34 -> 2-way bank aliasing = free).
template<bool DO_PROJ, bool DO_FFN, bool DO_QKV>
__global__ __launch_bounds__(256) void rowengine_kernel(
    const float* __restrict__ ob, const float* __restrict__ x_in,
    float* __restrict__ x_out,
    const float* __restrict__ Wo, const float* __restrict__ bo,
    const float* __restrict__ g1v, const float* __restrict__ b1v,
    const float* __restrict__ W1, const float* __restrict__ b1f,
    const float* __restrict__ W2, const float* __restrict__ b2f,
    const float* __restrict__ g2v, const float* __restrict__ b2v,
    const float* __restrict__ Wqkv, const float* __restrict__ bqkv,
    _Float16* __restrict__ qkh, _Float16* __restrict__ kbh,
    _Float16* __restrict__ vth)
{
  __shared__ float rowbuf[(DO_PROJ||DO_FFN) ? 64 : 1][34];
  __shared__ float zbuf[DO_FFN ? 4 : 1][64][34];
  __shared__ float stats[2][4][64];

  const int w = threadIdx.x >> 6;      // wave = column-slice id
  const int lane = threadIdx.x & 63;   // lane = local row
  const unsigned row = blockIdx.x*64u + lane;

  float y8[8];   // this wave's 8 cols of the LN1 output (resid for FFN)

  if (DO_PROJ) {
    // full o row (dup across waves; L1-cached)
    float orow[32];
    const float4* op = (const float4*)(ob + (size_t)row*32);
    #pragma unroll
    for (int i = 0; i < 8; ++i) {
      float4 t = op[i];
      orow[4*i]=t.x; orow[4*i+1]=t.y; orow[4*i+2]=t.z; orow[4*i+3]=t.w;
    }
    float t8[8];
    #pragma unroll
    for (int j = 0; j < 8; ++j) t8[j] = bo[8*w + j];
    for (int k = 0; k < 32; ++k) {
      float ov = orow[k];
      const float* wr = Wo + k*32 + 8*w;
      #pragma unroll
      for (int j = 0; j < 8; ++j) t8[j] += ov*wr[j];
    }
    { // residual (own 8-col slice)
      const float4* xp = (const float4*)(x_in + (size_t)row*32 + 8*w);
      float4 r0 = xp[0], r1 = xp[1];
      t8[0]+=r0.x; t8[1]+=r0.y; t8[2]+=r0.z; t8[3]+=r0.w;
      t8[4]+=r1.x; t8[5]+=r1.y; t8[6]+=r1.z; t8[7]+=r1.w;
    }
    float s1 = 0.f, s2 = 0.f;
    #pragma unroll
    for (int j = 0; j < 8; ++j) { s1 += t8[j]; s2 += t8[j]*t8[j]; }
    stats[0][w][lane] = s1; stats[1][w][lane] = s2;
    __syncthreads();
    float m = 0.f, q2 = 0.f;
    #pragma unroll
    for (int ww = 0; ww < 4; ++ww) { m += stats[0][ww][lane]; q2 += stats[1][ww][lane]; }
    m *= (1.f/32.f);
    float var = q2*(1.f/32.f) - m*m;
    float rinv = rsqrtf(var + 1e-5f);
    #pragma unroll
    for (int j = 0; j < 8; ++j)
      y8[j] = (t8[j]-m)*rinv*g1v[8*w+j] + b1v[8*w+j];
    #pragma unroll
    for (int j = 0; j < 4; ++j)
      *(float2*)&rowbuf[lane][8*w + 2*j] = make_float2(y8[2*j], y8[2*j+1]);
    __syncthreads();
  }

  float x8[8];   // final row values for this wave's 8 cols

  if (DO_FFN) {
    // full y row from LDS (stride 34 -> 2-way = free)
    float yr[32];
    #pragma unroll
    for (int kk = 0; kk < 16; ++kk) {
      float2 v = *(const float2*)&rowbuf[lane][2*kk];
      yr[2*kk] = v.x; yr[2*kk+1] = v.y;
    }
    float h[32];
    #pragma unroll
    for (int c = 0; c < 32; ++c) h[c] = b1f[32*w + c];
    for (int k = 0; k < 32; ++k) {
      float yv = yr[k];
      const float* wr = W1 + k*128 + 32*w;
      #pragma unroll
      for (int c = 0; c < 32; ++c) h[c] += yv*wr[c];
    }
    #pragma unroll
    for (int c = 0; c < 32; ++c) h[c] = fmaxf(h[c], 0.f);
    float z[32];
    #pragma unroll
    for (int j = 0; j < 32; ++j) z[j] = 0.f;
    for (int c = 0; c < 32; ++c) {
      float hv = h[c];
      const float* wr = W2 + (32*w + c)*32;
      #pragma unroll
      for (int j = 0; j < 32; ++j) z[j] += hv*wr[j];
    }
    #pragma unroll
    for (int j = 0; j < 16; ++j)
      *(float2*)&zbuf[w][lane][2*j] = make_float2(z[2*j], z[2*j+1]);
    __syncthreads();
    float y2[8];
    #pragma unroll
    for (int j = 0; j < 8; ++j) y2[j] = b2f[8*w+j] + yr[8*w+j];
    #pragma unroll
    for (int ww = 0; ww < 4; ++ww) {
      #pragma unroll
      for (int j = 0; j < 4; ++j) {
        float2 v = *(const float2*)&zbuf[ww][lane][8*w + 2*j];
        y2[2*j] += v.x; y2[2*j+1] += v.y;
      }
    }
    float s1 = 0.f, s2 = 0.f;
    #pragma unroll
    for (int j = 0; j < 8; ++j) { s1 += y2[j]; s2 += y2[j]*y2[j]; }
    stats[0][w][lane] = s1; stats[1][w][lane] = s2;
    __syncthreads();
    float m = 0.f, q2 = 0.f;
    #pragma unroll
    for (int ww = 0; ww < 4; ++ww) { m += stats[0][ww][lane]; q2 += stats[1][ww][lane]; }
    m *= (1.f/32.f);
    float var = q2*(1.f/32.f) - m*m;
    float rinv = rsqrtf(var + 1e-5f);
    #pragma unroll
    for (int j = 0; j < 8; ++j)
      x8[j] = (y2[j]-m)*rinv*g2v[8*w+j] + b2v[8*w+j];
    { // write final x (this wave's slice)
      float4* xo = (float4*)(x_out + (size_t)row*32 + 8*w);
      xo[0] = make_float4(x8[0],x8[1],x8[2],x8[3]);
      xo[1] = make_float4(x8[4],x8[5],x8[6],x8[7]);
    }
    if (DO_QKV) {
      #pragma unroll
      for (int j = 0; j < 4; ++j)
        *(float2*)&rowbuf[lane][8*w + 2*j] = make_float2(x8[2*j], x8[2*j+1]);
      __syncthreads();
    }
  }

  if (DO_QKV) {
    float xr[32];
    if (DO_PROJ || DO_FFN) {
      #pragma unroll
      for (int kk = 0; kk < 16; ++kk) {
        float2 v = *(const float2*)&rowbuf[lane][2*kk];
        xr[2*kk] = v.x; xr[2*kk+1] = v.y;
      }
    } else {
      const float4* xp = (const float4*)(x_in + (size_t)row*32);
      #pragma unroll
      for (int i = 0; i < 8; ++i) {
        float4 t = xp[i];
        xr[4*i]=t.x; xr[4*i+1]=t.y; xr[4*i+2]=t.z; xr[4*i+3]=t.w;
      }
    }
    unsigned b = row / (unsigned)NPOS;
    unsigned prow = row - b*(unsigned)NPOS;
    #pragma unroll
    for (int g = 0; g < 3; ++g) {
      const int cb = 24*w + 8*g;           // wave-uniform col base
      float a8[8];
      #pragma unroll
      for (int j = 0; j < 8; ++j) a8[j] = bqkv[cb + j];
      for (int k = 0; k < 32; ++k) {
        float xv = xr[k];
        const float* wr = Wqkv + k*96 + cb;
        #pragma unroll
        for (int j = 0; j < 8; ++j) a8[j] += xv*wr[j];
      }
      const int sec = cb >> 5;             // 0=Q 1=K 2=V
      const int hh  = (cb & 31) >> 3;
      const size_t bh = (size_t)(b*4 + hh);
      if (sec == 0) {
        half8 q;
        #pragma unroll
        for (int j = 0; j < 8; ++j) q[j] = (_Float16)(a8[j]*QSCALE);
        *(half8*)(qkh + (bh*NPOS + prow)*8) = q;
      } else if (sec == 1) {
        half8 kv;
        #pragma unroll
        for (int j = 0; j < 8; ++j) kv[j] = (_Float16)a8[j];
        *(half8*)(kbh + (bh*NPOS + prow)*8) = kv;
      } else {
        #pragma unroll
        for (int j = 0; j < 8; ++j)
          vth[(bh*8 + j)*NPOS + prow] = (_Float16)a8[j];
      }
    }
  }
}

// ------------------------------------------------------------------ attn ----
// Block per (b,h), 512 threads = 8 waves. MFMA 16x16x16 f16.
#define KSTR 24
#define VSTR 664
__global__ __launch_bounds__(512) void attn_kernel(
    const _Float16* __restrict__ qkh, const _Float16* __restrict__ kbh,
    const _Float16* __restrict__ vth, float* __restrict__ ob)
{
  __shared__ _Float16 Klds[656*KSTR];
  __shared__ _Float16 VTlds[16*VSTR];
  int bh = blockIdx.x;
  int b = bh >> 2, h = bh & 3;
  int tid = threadIdx.x;
  const half4 z4 = {0,0,0,0};
  for (int r = tid; r < 656; r += 512) {
    half4 a = z4, c = z4;
    if (r < NPOS) {
      a = *(const half4*)(kbh + ((size_t)bh*NPOS + r)*8);
      c = *(const half4*)(kbh + ((size_t)bh*NPOS + r)*8 + 4);
    }
    *(half4*)(Klds + r*KSTR)      = a;
    *(half4*)(Klds + r*KSTR + 4)  = c;
    *(half4*)(Klds + r*KSTR + 8)  = z4;
    *(half4*)(Klds + r*KSTR + 12) = z4;
  }
  for (int c = tid; c < 16*166; c += 512) {
    int d = c / 166, kc = (c % 166)*4;
    half4 v = z4;
    if (d < 8 && kc < 652)
      v = *(const half4*)(vth + ((size_t)bh*8 + d)*NPOS + kc);
    *(half4*)(VTlds + d*VSTR + kc) = v;
  }
  __syncthreads();

  int wave = tid >> 6, lane = tid & 63;
  int q16 = lane & 15;
  int kg  = lane >> 4;
  const float4v zc = {0.f,0.f,0.f,0.f};

  for (int qt = wave; qt < 41; qt += 8) {
    int qrow = qt*16 + q16;
    int qrc = qrow < NPOS ? qrow : NPOS-1;
    half4 qf = z4;
    if (kg < 2)
      qf = *(const half4*)(qkh + ((size_t)bh*NPOS + qrc)*8 + kg*4);
    float4v o = zc;
    float den = 0.f;
    for (int kt = 0; kt < 40; ++kt) {
      half4 kf = *(const half4*)(Klds + (kt*16 + q16)*KSTR + kg*4);
      float4v s = __builtin_amdgcn_mfma_f32_16x16x16f16(kf, qf, zc, 0, 0, 0);
      float p0 = __builtin_amdgcn_exp2f(s[0]);
      float p1 = __builtin_amdgcn_exp2f(s[1]);
      float p2 = __builtin_amdgcn_exp2f(s[2]);
      float p3 = __builtin_amdgcn_exp2f(s[3]);
      den += (p0+p1)+(p2+p3);
      half4 pf; pf[0]=(_Float16)p0; pf[1]=(_Float16)p1; pf[2]=(_Float16)p2; pf[3]=(_Float16)p3;
      half4 vf = *(const half4*)(VTlds + q16*VSTR + kt*16 + kg*4);
      o = __builtin_amdgcn_mfma_f32_16x16x16f16(pf, vf, o, 0, 0, 0);
    }
    {
      half4 kf = *(const half4*)(Klds + (640 + q16)*KSTR + kg*4);
      float4v s = __builtin_amdgcn_mfma_f32_16x16x16f16(kf, qf, zc, 0, 0, 0);
      float p0 = __builtin_amdgcn_exp2f(s[0]);
      float p1 = __builtin_amdgcn_exp2f(s[1]);
      float p2 = __builtin_amdgcn_exp2f(s[2]);
      float p3 = __builtin_amdgcn_exp2f(s[3]);
      if (kg == 3) { p0=0.f; p1=0.f; p2=0.f; p3=0.f; }
      den += (p0+p1)+(p2+p3);
      half4 pf; pf[0]=(_Float16)p0; pf[1]=(_Float16)p1; pf[2]=(_Float16)p2; pf[3]=(_Float16)p3;
      half4 vf = *(const half4*)(VTlds + q16*VSTR + 640 + kg*4);
      o = __builtin_amdgcn_mfma_f32_16x16x16f16(pf, vf, o, 0, 0, 0);
    }
    float den_full = den;
    den_full += __shfl_xor(den_full, 16);
    den_full += __shfl_xor(den_full, 32);
    float dq[4];
    #pragma unroll
    for (int reg = 0; reg < 4; ++reg)
      dq[reg] = __shfl(den_full, 4*kg + reg);
    if (q16 < 8) {
      #pragma unroll
      for (int reg = 0; reg < 4; ++reg) {
        int qo = qt*16 + 4*kg + reg;
        if (qo < NPOS) {
          ob[((size_t)(b*NPOS + qo))*32 + h*8 + q16] = o[reg] / dq[reg];
        }
      }
    }
  }
}

// --------------------------------------------------------------- readout ----
__global__ __launch_bounds__(256) void readout_kernel(
    const float* __restrict__ x,
    const float* __restrict__ Wtraj, const float* __restrict__ btraj,
    const float* __restrict__ Wint, const float* __restrict__ bint,
    float* __restrict__ dout)
{
  int idx = blockIdx.x*256 + threadIdx.x;
  if (idx >= NB*NVEH) return;
  int b = idx >> 6, n = idx & 63;
  int z = n >> 4, v = n & 15;
  int base = 4 + z*ZSTRIDE + 2 + v*10;
  float acc[16];
  #pragma unroll
  for (int i = 0; i < 16; ++i) acc[i] = btraj[i];
  for (int t = 0; t < 4; ++t) {
    const float* xr = x + ((size_t)(b*NPOS + base + 6 + t))*32;
    for (int k = 0; k < 32; ++k) {
      float xv = xr[k];
      const float* wr = Wtraj + (t*32 + k)*16;
      #pragma unroll
      for (int i = 0; i < 16; ++i) acc[i] += xv*wr[i];
    }
  }
  float* to = dout + (size_t)idx*16;
  #pragma unroll
  for (int i = 0; i < 16; ++i) to[i] = acc[i];
  float ai[8];
  #pragma unroll
  for (int j = 0; j < 8; ++j) ai[j] = bint[j];
  for (int t = 0; t < 2; ++t) {
    const float* xr = x + ((size_t)(b*NPOS + base + 4 + t))*32;
    for (int k = 0; k < 32; ++k) {
      float xv = xr[k];
      const float* wr = Wint + (t*32 + k)*8;
      #pragma unroll
      for (int j = 0; j < 8; ++j) ai[j] += xv*wr[j];
    }
  }
  float* io = dout + 131072 + (size_t)idx*8;
  #pragma unroll
  for (int j = 0; j < 8; ++j) io[j] = ai[j];
}

// ---------------------------------------------------------------- launch ----
extern "C" void kernel_launch(void* const* d_in, const int* in_sizes, int n_in,
                              void* d_out, int out_size, void* d_ws, size_t ws_size,
                              hipStream_t stream)
{
  const float* states  = (const float*)d_in[0];
  const float* road_ctx= (const float*)d_in[1];
  const float* pos_emb = (const float*)d_in[2];
  const float* Wp    = (const float*)d_in[4];  const float* bp    = (const float*)d_in[5];
  const float* Wv    = (const float*)d_in[6];  const float* bv    = (const float*)d_in[7];
  const float* Wh    = (const float*)d_in[8];  const float* bh    = (const float*)d_in[9];
  const float* Wc    = (const float*)d_in[10]; const float* bc    = (const float*)d_in[11];
  const float* Wflow = (const float*)d_in[12]; const float* bflow = (const float*)d_in[13];
  const float* Wsig  = (const float*)d_in[14]; const float* bsig  = (const float*)d_in[15];
  const float* Wtraj = (const float*)d_in[16]; const float* btraj = (const float*)d_in[17];
  const float* Wint  = (const float*)d_in[18]; const float* bint  = (const float*)d_in[19];
  const float* Wqkv  = (const float*)d_in[20]; const float* bqkv  = (const float*)d_in[21];
  const float* Wo    = (const float*)d_in[22]; const float* bo    = (const float*)d_in[23];
  const float* g1    = (const float*)d_in[24]; const float* b1ln  = (const float*)d_in[25];
  const float* W1    = (const float*)d_in[26]; const float* b1    = (const float*)d_in[27];
  const float* W2    = (const float*)d_in[28]; const float* b2    = (const float*)d_in[29];
  const float* g2    = (const float*)d_in[30]; const float* b2ln  = (const float*)d_in[31];

  float* x  = (float*)d_ws;
  float* ob = x + (size_t)MROWS*32;
  _Float16* qkh = (_Float16*)(ob + (size_t)MROWS*32);
  _Float16* kbh = qkh + (size_t)512*NPOS*8;
  _Float16* vth = kbh + (size_t)512*NPOS*8;

  canvas_kernel<<<NB, 256, 0, stream>>>(states, road_ctx, pos_emb,
      Wp, bp, Wv, bv, Wh, bh, Wc, bc, Wflow, bflow, Wsig, bsig, x);

  const int rowBlocks = MROWS/64;   // 1304

  // layer 0 QKV (qkv only, x -> q/k/v)
  rowengine_kernel<false,false,true><<<rowBlocks, 256, 0, stream>>>(
      nullptr, x, nullptr,
      nullptr, nullptr, nullptr, nullptr,
      nullptr, nullptr, nullptr, nullptr, nullptr, nullptr,
      Wqkv, bqkv, qkh, kbh, vth);

  attn_kernel<<<NB*NH, 512, 0, stream>>>(qkh, kbh, vth, ob);

  // layer 0 proj+LN+FFN+LN, fused with layer 1 QKV
  rowengine_kernel<true,true,true><<<rowBlocks, 256, 0, stream>>>(
      ob, x, x,
      Wo, bo, g1, b1ln,
      W1, b1, W2, b2, g2, b2ln,
      Wqkv + 32*96, bqkv + 96, qkh, kbh, vth);

  attn_kernel<<<NB*NH, 512, 0, stream>>>(qkh, kbh, vth, ob);

  // layer 1 proj+LN+FFN+LN (no qkv)
  rowengine_kernel<true,true,false><<<rowBlocks, 256, 0, stream>>>(
      ob, x, x,
      Wo + 32*32, bo + 32, g1 + 32, b1ln + 32,
      W1 + 32*128, b1 + 128, W2 + 128*32, b2 + 32, g2 + 32, b2ln + 32,
      nullptr, nullptr, nullptr, nullptr, nullptr);

  readout_kernel<<<(NB*NVEH + 255)/256, 256, 0, stream>>>(
      x, Wtraj, btraj, Wint, bint, (float*)d_out);
}